// Round 1
// baseline (1184.610 us; speedup 1.0000x reference)
//
#include <hip/hip_runtime.h>

// lqformerattention on MI355X (gfx950).
// Pipeline: proj_gemm<0>(query) -> qhat[8192][512] f16
//           proj_gemm<0>(key)   -> khat[8192][512] f16
//           proj_gemm<1>(value) -> vhatT[b][2048 feat][1024 kpos] f16 (transposed)
//           attn_fused: per (b,h,16 q-rows): QK^T mfma -> exp -> P (LDS, swizzled)
//                       -> rowsum -> normalize+store weights -> PV mfma -> O.
// All matmul math in fp16 MFMA (16x16x32) with fp32 accumulation; softmax in fp32.
// Workspace usage: 48 MiB (qhat 8 + khat 8 + vhatT 32).

typedef _Float16 f16;
typedef _Float16 f16x8 __attribute__((ext_vector_type(8)));
typedef _Float16 f16x4 __attribute__((ext_vector_type(4)));
typedef float f32x4 __attribute__((ext_vector_type(4)));
typedef float f32x8 __attribute__((ext_vector_type(8)));

// ---------------------------------------------------------------------------
// proj_gemm: Y = X(MxK) @ W(NxK)^T + bias, fp32 in, f16 out.
// 128x128 block tile, BK=32, 256 threads = 4 waves in 2x2, mfma_f32_16x16x32_f16.
// LDS holds A/B tiles in *fragment order*: slot (mtile, lane) <-> the exact half8
// lane `lane` needs for m-tile `mtile` -> staging writes and frag reads are both
// lane-linear b128 ops with all-distinct 16B granules (no bank imbalance).
// MODE 0: natural Y[M][N].  MODE 1: v-proj transposed Y[(b*2048+n)*1024 + kpos],
//         where flat m = b*1024 + kpos (128-row blocks never straddle b).
// ---------------------------------------------------------------------------
template <int MODE>
__global__ __launch_bounds__(256) void proj_gemm(
    const float* __restrict__ X, const float* __restrict__ W,
    const float* __restrict__ bias, f16* __restrict__ Y, int K, int N) {
  __shared__ f16 Asf[4096];  // 8 mtiles * 64 lanes * 8 halves = 8 KiB
  __shared__ f16 Bsf[4096];
  const int t = threadIdx.x;
  const int lane = t & 63;
  const int w = t >> 6;
  const int wm = w >> 1, wn = w & 1;
  const int quad = lane >> 4, col = lane & 15;
  const long m0 = (long)blockIdx.x * 128;
  const int n0 = blockIdx.y * 128;

  f32x4 acc[4][4];
#pragma unroll
  for (int i = 0; i < 4; ++i)
#pragma unroll
    for (int j = 0; j < 4; ++j) acc[i][j] = (f32x4){0.f, 0.f, 0.f, 0.f};

  for (int k0 = 0; k0 < K; k0 += 32) {
    __syncthreads();
    // stage A (X rows) and B (W rows; B[k][n] = W[n][k]) as fp16 fragments
#pragma unroll
    for (int half = 0; half < 2; ++half) {
      const int s = t + half * 256;       // slot 0..511
      const int row = s >> 2;             // tile-local row 0..127
      const int kq = s & 3;               // which 8-wide k chunk
      f32x8 xa = *(const f32x8*)(X + (m0 + row) * (long)K + k0 + kq * 8);
      f32x8 wa = *(const f32x8*)(W + ((long)n0 + row) * (long)K + k0 + kq * 8);
      const int off = (((row >> 4) * 64) + (row & 15) + (kq << 4)) * 8;
      *(f16x8*)&Asf[off] = __builtin_convertvector(xa, f16x8);
      *(f16x8*)&Bsf[off] = __builtin_convertvector(wa, f16x8);
    }
    __syncthreads();
    f16x8 a[4], b[4];
#pragma unroll
    for (int i = 0; i < 4; ++i)
      a[i] = *(const f16x8*)&Asf[((wm * 4 + i) * 64 + lane) * 8];
#pragma unroll
    for (int j = 0; j < 4; ++j)
      b[j] = *(const f16x8*)&Bsf[((wn * 4 + j) * 64 + lane) * 8];
#pragma unroll
    for (int i = 0; i < 4; ++i)
#pragma unroll
      for (int j = 0; j < 4; ++j)
        acc[i][j] = __builtin_amdgcn_mfma_f32_16x16x32_f16(a[i], b[j], acc[i][j], 0, 0, 0);
  }

  // epilogue: C/D layout col=lane&15, row=quad*4+reg (m89-verified mapping)
#pragma unroll
  for (int j = 0; j < 4; ++j) {
    const int gn = n0 + (wn * 4 + j) * 16 + col;
    const float bv = bias[gn];
#pragma unroll
    for (int i = 0; i < 4; ++i) {
      const long gm0 = m0 + (wm * 4 + i) * 16 + quad * 4;  // rows gm0..gm0+3
      if (MODE == 0) {
#pragma unroll
        for (int r = 0; r < 4; ++r)
          Y[(gm0 + r) * (long)N + gn] = (f16)(acc[i][j][r] + bv);
      } else {
        const long bb = gm0 >> 10;            // batch
        const int kpos = (int)(gm0 & 1023);   // position within batch
        f16x4 ov;
#pragma unroll
        for (int r = 0; r < 4; ++r) ov[r] = (f16)(acc[i][j][r] + bv);
        *(f16x4*)&Y[(bb * 2048 + gn) * 1024 + kpos] = ov;  // 8B store, aligned
      }
    }
  }
}

// ---------------------------------------------------------------------------
// attn_fused: one block = (b, h, 16 q-rows). 256 threads = 4 waves.
//   QK: A-frag (q rows, fixed) and B-frags (k rows) loaded straight from global
//       (both are 16B-contiguous half8 in qhat/khat natural layout).
//       Each wave owns n-tiles nt = w, w+4, ... (16 of 64).
//   e = exp(s/sqrt(32) + maskfix) written to LDS P[16][1024] f16 with an XOR
//       granule swizzle (granule g -> g ^ (row&7)) so PV A-frag b128 reads and
//       the normalize-loop b128 reads are conflict-free.
//   Fixed-shift softmax: exp without max subtraction (logits <= ~8, fp32 safe);
//   mathematically identical to the reference's max-subtracted softmax.
//   Row sums -> linv in LDS; P normalized in place (= attn_weights, stored
//   coalesced fp32); then PV mfma with B-frags direct from vhatT.
// ---------------------------------------------------------------------------
__global__ __launch_bounds__(256) void attn_fused(
    const f16* __restrict__ qhat, const f16* __restrict__ khat,
    const f16* __restrict__ vhatT, const float* __restrict__ mask,
    float* __restrict__ outO, float* __restrict__ outW) {
  __shared__ f16 P[16 * 1024];       // 32 KiB
  __shared__ float lpart[4][16];
  __shared__ float linv16[16];

  const int t = threadIdx.x;
  const int lane = t & 63;
  const int w = t >> 6;
  const int quad = lane >> 4, col = lane & 15;
  const int qt = blockIdx.x;         // 0..63  -> q0 = qt*16
  const int bh = blockIdx.y;         // 0..127
  const int b = bh >> 4, h = bh & 15;
  const int q0 = qt * 16;

  // A fragment: q rows q0..q0+15, head dims h*32..h*32+31 (full contraction)
  const f16x8 afrag = *(const f16x8*)(qhat +
      ((long)(b * 1024 + q0 + col)) * 512 + h * 32 + quad * 8);

  const float sc = 0.17677669529663687f;  // 1/sqrt(32)
  const f32x4 zero = {0.f, 0.f, 0.f, 0.f};
  float lacc[4] = {0.f, 0.f, 0.f, 0.f};

  for (int nt = w; nt < 64; nt += 4) {
    const f16x8 bfrag = *(const f16x8*)(khat +
        ((long)(b * 1024 + nt * 16 + col)) * 512 + h * 32 + quad * 8);
    f32x4 c = __builtin_amdgcn_mfma_f32_16x16x32_f16(afrag, bfrag, zero, 0, 0, 0);
    const int kpos = nt * 16 + col;
    const int g = kpos >> 3;
    const long mrow0 = (long)b * 1024 + q0 + quad * 4;
#pragma unroll
    for (int r = 0; r < 4; ++r) {
      float mv = mask[(mrow0 + r) * 1024 + kpos];
      mv = (mv == 0.0f) ? -10000.0f : mv;  // masked_fill semantics
      const float e = __expf(c[r] * sc + mv);
      lacc[r] += e;
      const int qrow = quad * 4 + r;
      P[qrow * 1024 + ((g ^ (qrow & 7)) << 3) + (kpos & 7)] = (f16)e;
    }
  }

  // row sums: reduce over the 16 columns held across lane bits 0..3
#pragma unroll
  for (int r = 0; r < 4; ++r) {
    float v = lacc[r];
#pragma unroll
    for (int d = 1; d < 16; d <<= 1) v += __shfl_xor(v, d, 64);
    lacc[r] = v;
  }
  if (col == 0) {
#pragma unroll
    for (int r = 0; r < 4; ++r) lpart[w][quad * 4 + r] = lacc[r];
  }
  __syncthreads();
  if (t < 16)
    linv16[t] = 1.0f / (lpart[0][t] + lpart[1][t] + lpart[2][t] + lpart[3][t]);
  __syncthreads();

  // normalize P in place and store attn_weights (coalesced fp32)
  float* wbase = outW + ((long)bh * 1024 + q0) * 1024;
#pragma unroll
  for (int i = 0; i < 8; ++i) {
    const int idx = i * 2048 + t * 8;
    const int row = idx >> 10;
    const int c0 = idx & 1023;
    const float li = linv16[row];
    const int poff = row * 1024 + ((((c0 >> 3) ^ (row & 7)) << 3));
    f16x8 pv = *(const f16x8*)&P[poff];
    f32x4 o0, o1;
    f16x8 pn;
#pragma unroll
    for (int r = 0; r < 4; ++r) {
      const float w0 = (float)pv[r] * li;
      const float w1 = (float)pv[r + 4] * li;
      o0[r] = w0; o1[r] = w1;
      pn[r] = (f16)w0; pn[r + 4] = (f16)w1;
    }
    *(f16x8*)&P[poff] = pn;
    *(f32x4*)&wbase[(long)row * 1024 + c0] = o0;
    *(f32x4*)&wbase[(long)row * 1024 + c0 + 4] = o1;
  }
  __syncthreads();

  // PV: O[16 x 128] = P[16 x 1024] @ V[1024 x 128]; wave w owns out cols w*32..+31
  f32x4 oacc[2];
  oacc[0] = zero; oacc[1] = zero;
  const f16* vbase = vhatT + ((long)b * 2048 + h * 128 + w * 32) * 1024;
  for (int kc = 0; kc < 32; ++kc) {
    f16x8 bf[2], af;
#pragma unroll
    for (int n2 = 0; n2 < 2; ++n2)
      bf[n2] = *(const f16x8*)&vbase[(long)(n2 * 16 + col) * 1024 + kc * 32 + quad * 8];
    {
      const int row = col;               // A-frag: m = lane&15
      const int g = kc * 4 + quad;
      af = *(const f16x8*)&P[row * 1024 + ((g ^ (row & 7)) << 3)];
    }
#pragma unroll
    for (int n2 = 0; n2 < 2; ++n2)
      oacc[n2] = __builtin_amdgcn_mfma_f32_16x16x32_f16(af, bf[n2], oacc[n2], 0, 0, 0);
  }
#pragma unroll
  for (int n2 = 0; n2 < 2; ++n2)
#pragma unroll
    for (int r = 0; r < 4; ++r) {
      const int qrow = quad * 4 + r;
      outO[((long)(b * 1024 + q0 + qrow)) * 2048 + h * 128 + w * 32 + n2 * 16 + col] =
          oacc[n2][r];
    }
}

// ---------------------------------------------------------------------------
extern "C" void kernel_launch(void* const* d_in, const int* in_sizes, int n_in,
                              void* d_out, int out_size, void* d_ws, size_t ws_size,
                              hipStream_t stream) {
  const float* query = (const float*)d_in[0];
  const float* key   = (const float*)d_in[1];
  const float* value = (const float*)d_in[2];
  const float* mask  = (const float*)d_in[3];
  const float* qW = (const float*)d_in[4];
  const float* qb = (const float*)d_in[5];
  const float* kW = (const float*)d_in[6];
  const float* kb = (const float*)d_in[7];
  const float* vW = (const float*)d_in[8];
  const float* vb = (const float*)d_in[9];

  float* outO = (float*)d_out;                        // [8][1024][2048]
  float* outW = outO + (size_t)8 * 1024 * 2048;       // [8][16][1024][1024]

  char* ws = (char*)d_ws;                             // needs 48 MiB
  f16* qhat  = (f16*)ws;                              // [8192][512]
  f16* khat  = (f16*)(ws + ((size_t)8 << 20));        // [8192][512]
  f16* vhatT = (f16*)(ws + ((size_t)16 << 20));       // [8][2048][1024]

  proj_gemm<0><<<dim3(64, 4), 256, 0, stream>>>(query, qW, qb, qhat, 512, 512);
  proj_gemm<0><<<dim3(64, 4), 256, 0, stream>>>(key, kW, kb, khat, 512, 512);
  proj_gemm<1><<<dim3(64, 16), 256, 0, stream>>>(value, vW, vb, vhatT, 2048, 2048);
  attn_fused<<<dim3(64, 128), 256, 0, stream>>>(qhat, khat, vhatT, mask, outO, outW);
}